// Round 20
// baseline (50.795 us; speedup 1.0000x reference)
//
#include <hip/hip_runtime.h>

#define P_TOT 30000
#define NPT   100
#define COUT  64
#define PROWS 144   // partials rows per block (138 used, padded)

typedef __attribute__((ext_vector_type(8)))  short bf16x8;
typedef __attribute__((ext_vector_type(16))) float f32x16;

static constexpr float VXf   = 0.16f;
static constexpr float VYf   = 0.16f;
static constexpr float XOFFf = 0.08f;            // VX/2 + 0.0
static constexpr float YOFFf = 0.08f - 39.68f;   // VY/2 + y_min
static constexpr float INV_M = 1.0f / 3000000.0f; // 1/(P*N)
static constexpr float NEGI  = -3.0e38f;

__device__ inline float wred(float v) {
#pragma unroll
  for (int d = 1; d < 64; d <<= 1) v += __shfl_xor(v, d);
  return v;
}

// (bf16(hi) << 16) | bf16(lo)
__device__ inline unsigned pack_bf2(float lo, float hi) {
  return (__float_as_uint(hi) & 0xFFFF0000u) | (__float_as_uint(lo) >> 16);
}

union AF { bf16x8 v; unsigned u[4]; };

// ---- max-only fold ----
__device__ inline void fold_fullM(const f32x16& c, float& zm) {
#pragma unroll
  for (int r = 0; r < 8; ++r)
    zm = fmaxf(fmaxf(zm, c[2 * r]), c[2 * r + 1]);   // v_max3 chains
}

__device__ inline void fold_maskM(const f32x16& c, int thresh, float& zm) {
#pragma unroll
  for (int r = 0; r < 16; ++r) {
    const int ro = (r & 3) + 8 * (r >> 2);
    zm = fmaxf(zm, (ro < thresh) ? c[r] : NEGI);  // exclude zero-staged pad rows
  }
}

// One MFMA pair (both channel halves) + max fold for a tile.
#define TILE_BODY(U0, U1, TFULL, THRESH)                                        \
  {                                                                             \
    unsigned u0_ = (U0), u1_ = (U1);                                            \
    if (lane >= 32) { u0_ = 0u; u1_ = 0u; }  /* k-group 1 = zero pad */         \
    AF af;                                                                      \
    af.u[0] = u0_; af.u[1] = u1_; af.u[2] = 0; af.u[3] = 0;                     \
    {                                                                           \
      f32x16 c0 = __builtin_amdgcn_mfma_f32_32x32x16_bf16(af.v, bf0.v, z16, 0, 0, 0); \
      if (TFULL) fold_fullM(c0, zm0);                                           \
      else       fold_maskM(c0, (THRESH), zm0);                                 \
    }                                                                           \
    {                                                                           \
      f32x16 c1 = __builtin_amdgcn_mfma_f32_32x32x16_bf16(af.v, bf1.v, z16, 0, 0, 0); \
      if (TFULL) fold_fullM(c1, zm1);                                           \
      else       fold_maskM(c1, (THRESH), zm1);                                 \
    }                                                                           \
  }

// K1: r19 LDS-free structure (register A-fragments, prefetch, 4 static tiles)
// with the fold reduced to MAX-ONLY. Stats in closed form (r13-verified math):
//   zs_p   = ce . Sv_p                      (Sv = 4 wreds of masked values)
//   sum   += zs + np*b                      (per-lane accumulate)
//   sqb   += b*(2*zs + np*b)
//   M_G    = sum qq^T over valid points     (mac[10], per-lane, wred at end)
// K3 applies sumsq_c = ce^T M_G ce + sqb_c.
__global__ __launch_bounds__(256) void k1_mfma(
    const float4* __restrict__ feat, const int* __restrict__ npts,
    const int* __restrict__ coords, const float* __restrict__ W,
    float* __restrict__ ymax, float* __restrict__ partials, int nb) {
  const int lane = threadIdx.x & 63;
  const int wv   = threadIdx.x >> 6;
  const int wave_id = blockIdx.x * 4 + wv;
  const int nwaves  = nb * 4;
  const int rbase   = (lane >> 5) * 4;

  // per-channel weights, affine-folded: ce = (w0+w4+w7, w1+w5+w8, w2+w6, w3)
  float wr[9];
#pragma unroll
  for (int i = 0; i < 9; i++) wr[i] = W[lane * 9 + i];
  const float ce0 = wr[0] + wr[4] + wr[7];
  const float ce1 = wr[1] + wr[5] + wr[8];
  const float ce2 = wr[2] + wr[6];
  const float ce3 = wr[3];

  // B fragments: lane -> channel n*32+(lane&31), real k=0..3 in slots u0,u1
  AF bf0, bf1;
  {
    const unsigned p01 = pack_bf2(ce0, ce1);
    const unsigned p23 = pack_bf2(ce2, ce3);
    const int s0 = lane & 31, s1 = 32 + (lane & 31);
    unsigned b0a = (unsigned)__shfl((int)p01, s0);
    unsigned b0b = (unsigned)__shfl((int)p23, s0);
    unsigned b1a = (unsigned)__shfl((int)p01, s1);
    unsigned b1b = (unsigned)__shfl((int)p23, s1);
    if (lane >= 32) { b0a = b0b = b1a = b1b = 0; }
    bf0.u[0] = b0a; bf0.u[1] = b0b; bf0.u[2] = 0; bf0.u[3] = 0;
    bf1.u[0] = b1a; bf1.u[1] = b1b; bf1.u[2] = 0; bf1.u[3] = 0;
  }

  const f32x16 z16 = {0.f};
  float sum = 0.f, sqb = 0.f;
  float mac[10];
#pragma unroll
  for (int i = 0; i < 10; i++) mac[i] = 0.f;

  // prologue: load pillar wave_id
  int p = wave_id;
  float4 a0 = make_float4(0.f, 0.f, 0.f, 0.f), a1 = a0;
  int np = 1, cx = 0, cy = 0;
  if (p < P_TOT) {
    const float4* fp = feat + (size_t)p * NPT;
    a0 = fp[lane];
    if (lane < 36) a1 = fp[lane + 64];
    np = npts[p];
    cx = coords[p * 4 + 3];
    cy = coords[p * 4 + 2];
  }

  while (p < P_TOT) {
    const int pn = p + nwaves;
    float4 b0 = make_float4(0.f, 0.f, 0.f, 0.f), b1 = b0;
    int npn = 1, cxn = 0, cyn = 0;
    if (pn < P_TOT) {
      const float4* fpn = feat + (size_t)pn * NPT;
      b0 = fpn[lane];
      if (lane < 36) b1 = fpn[lane + 64];
      npn = npts[pn];
      cxn = coords[pn * 4 + 3];
      cyn = coords[pn * 4 + 2];
    }

    // masked f32 values (exact, for stats) + packed bf16 A-rows (for MFMA)
    const bool v0 = lane < np;
    const bool v1 = lane + 64 < np;   // implies lane < 36 since np <= 100
    const float m0x = v0 ? a0.x : 0.f, m0y = v0 ? a0.y : 0.f;
    const float m0z = v0 ? a0.z : 0.f, m0w = v0 ? a0.w : 0.f;
    const float m1x = v1 ? a1.x : 0.f, m1y = v1 ? a1.y : 0.f;
    const float m1z = v1 ? a1.z : 0.f, m1w = v1 ? a1.w : 0.f;

    unsigned pk0 = pack_bf2(a0.x, a0.y), pk1 = pack_bf2(a0.z, a0.w);
    unsigned pk2 = pack_bf2(a1.x, a1.y), pk3 = pack_bf2(a1.z, a1.w);
    if (!v0) { pk0 = 0u; pk1 = 0u; }
    if (!v1) { pk2 = 0u; pk3 = 0u; }

    // global M accumulation (10 unique entries x 2 point slots, exact f32)
    mac[0] = fmaf(m0x, m0x, fmaf(m1x, m1x, mac[0]));
    mac[1] = fmaf(m0x, m0y, fmaf(m1x, m1y, mac[1]));
    mac[2] = fmaf(m0x, m0z, fmaf(m1x, m1z, mac[2]));
    mac[3] = fmaf(m0x, m0w, fmaf(m1x, m1w, mac[3]));
    mac[4] = fmaf(m0y, m0y, fmaf(m1y, m1y, mac[4]));
    mac[5] = fmaf(m0y, m0z, fmaf(m1y, m1z, mac[5]));
    mac[6] = fmaf(m0y, m0w, fmaf(m1y, m1w, mac[6]));
    mac[7] = fmaf(m0z, m0z, fmaf(m1z, m1z, mac[7]));
    mac[8] = fmaf(m0z, m0w, fmaf(m1z, m1w, mac[8]));
    mac[9] = fmaf(m0w, m0w, fmaf(m1w, m1w, mac[9]));

    // per-pillar reductions: raw xyz (for b, reference sums ALL 100 rows)
    // and masked sums Sv (for zs)
    const float sax = wred(a0.x + a1.x);
    const float say = wred(a0.y + a1.y);
    const float saz = wred(a0.z + a1.z);
    const float svx = wred(m0x + m1x);
    const float svy = wred(m0y + m1y);
    const float svz = wred(m0z + m1z);
    const float svw = wred(m0w + m1w);

    const float inv = 1.f / (float)np;
    const float cxc = (float)cx * VXf + XOFFf;
    const float cyc = (float)cy * VYf + YOFFf;
    float b = wr[4] * (sax * inv);
    b = fmaf(wr[5], say * inv, b);
    b = fmaf(wr[6], saz * inv, b);
    b = fmaf(wr[7], cxc, b);
    b = fmaf(wr[8], cyc, b);
    b = -b;

    float zs = ce0 * svx;
    zs = fmaf(ce1, svy, zs);
    zs = fmaf(ce2, svz, zs);
    zs = fmaf(ce3, svw, zs);

    // z-loop: 4 static tiles, A-fragments from registers, max-only fold
    float zm0 = NEGI, zm1 = NEGI;
    TILE_BODY(pk0, pk1, (np >= 32), np - rbase);                 // tile 0
    if (np > 32) {                                               // tile 1
      const unsigned s0 = (unsigned)__shfl_xor((int)pk0, 32);
      const unsigned s1 = (unsigned)__shfl_xor((int)pk1, 32);
      TILE_BODY(s0, s1, (np >= 64), np - 32 - rbase);
    }
    if (np > 64) {                                               // tile 2
      TILE_BODY(pk2, pk3, (np >= 96), np - 64 - rbase);
    }
    if (np > 96) {                                               // tile 3
      const unsigned s2 = (unsigned)__shfl_xor((int)pk2, 32);
      const unsigned s3 = (unsigned)__shfl_xor((int)pk3, 32);
      TILE_BODY(s2, s3, false, np - 96 - rbase);
    }

    // combine row-halves, pick this lane's channel half
    zm0 = fmaxf(zm0, __shfl_xor(zm0, 32));
    zm1 = fmaxf(zm1, __shfl_xor(zm1, 32));
    const float zm = (lane < 32) ? zm0 : zm1;   // channel = lane

    const float npf = (float)np;
    ymax[p * COUT + lane] = zm + b;
    sum += zs + npf * b;
    sqb += b * fmaf(npf, b, 2.f * zs);

    p = pn;
    a0 = b0; a1 = b1; np = npn; cx = cxn; cy = cyn;
  }

  // block reduction: 64 sum rows, 64 sqb rows, 10 M rows
  __syncthreads();
  __shared__ float rs[4][64], rq[4][64], rm[4][10];
  rs[wv][lane] = sum;
  rq[wv][lane] = sqb;
#pragma unroll
  for (int i = 0; i < 10; i++) {
    const float v = wred(mac[i]);
    if (lane == 0) rm[wv][i] = v;
  }
  __syncthreads();
  const int t = threadIdx.x;
  if (t < 128) {
    const int c = t & 63;
    float v;
    if (t < 64) v = rs[0][c] + rs[1][c] + rs[2][c] + rs[3][c];
    else        v = rq[0][c] + rq[1][c] + rq[2][c] + rq[3][c];
    partials[(size_t)blockIdx.x * PROWS + t] = v;
  } else if (t < 138) {
    const int i = t - 128;
    partials[(size_t)blockIdx.x * PROWS + t] =
        rm[0][i] + rm[1][i] + rm[2][i] + rm[3][i];
  }
}

// K2: 138 blocks (one per moment row), 256 threads each (r13-verified)
__global__ __launch_bounds__(256) void k2_reduce(
    const float* __restrict__ partials, int nb, float* __restrict__ S) {
  const int m = blockIdx.x;
  float s = 0.f;
  for (int b = threadIdx.x; b < nb; b += 256)
    s += partials[(size_t)b * PROWS + m];
  s = wred(s);
  __shared__ float t4[4];
  if ((threadIdx.x & 63) == 0) t4[threadIdx.x >> 6] = s;
  __syncthreads();
  if (threadIdx.x == 0) S[m] = t4[0] + t4[1] + t4[2] + t4[3];
}

// K3: finish in place on d_out. sumsq_c = ce^T M ce + sqb_c (r13-verified).
// gamma==1 => scale>0, so max commutes with the BN affine.
__global__ __launch_bounds__(256) void k3_finish(
    const int* __restrict__ npts, const float* __restrict__ S,
    const float* __restrict__ W, const float* __restrict__ gamma,
    const float* __restrict__ beta, float* __restrict__ out) {
  const int c  = threadIdx.x & 63;
  const int wv = threadIdx.x >> 6;
  const int p  = blockIdx.x * 4 + wv;   // 7500*4 == 30000

  float wr[9];
#pragma unroll
  for (int i = 0; i < 9; i++) wr[i] = W[c * 9 + i];
  const float ce0 = wr[0] + wr[4] + wr[7];
  const float ce1 = wr[1] + wr[5] + wr[8];
  const float ce2 = wr[2] + wr[6];
  const float ce3 = wr[3];

  const float sum = S[c];
  const float sqb = S[64 + c];
  float quad = ce0 * ce0 * S[128] + ce1 * ce1 * S[132] +
               ce2 * ce2 * S[135] + ce3 * ce3 * S[137];
  quad += 2.f * (ce0 * (ce1 * S[129] + ce2 * S[130] + ce3 * S[131]) +
                 ce1 * (ce2 * S[133] + ce3 * S[134]) +
                 ce2 * ce3 * S[136]);

  const float mean  = sum * INV_M;
  const float var   = (quad + sqb) * INV_M - mean * mean;
  const float scale = gamma[c] * rsqrtf(var + 0.001f);
  const float shift = beta[c] - mean * scale;

  const int np = npts[p];
  float v = fmaf(scale, out[p * COUT + c], shift);
  if (np < NPT) v = fmaxf(v, shift);   // padded positions contribute relu(shift)
  out[p * COUT + c] = fmaxf(v, 0.f);
}

extern "C" void kernel_launch(void* const* d_in, const int* in_sizes, int n_in,
                              void* d_out, int out_size, void* d_ws, size_t ws_size,
                              hipStream_t stream) {
  const float4* feat  = (const float4*)d_in[0];
  const int*   npts   = (const int*)d_in[1];
  const int*   coords = (const int*)d_in[2];
  const float* W      = (const float*)d_in[3];
  const float* gamma  = (const float*)d_in[4];
  const float* beta   = (const float*)d_in[5];
  float* out = (float*)d_out;

  int nb = 512;
  if (ws_size >= (size_t)(PROWS + 2048 * PROWS) * 4) nb = 2048;
  else if (ws_size >= (size_t)(PROWS + 1024 * PROWS) * 4) nb = 1024;

  float* S        = (float*)d_ws;     // PROWS floats
  float* partials = S + PROWS;        // nb*PROWS floats, block-major

  k1_mfma<<<nb, 256, 0, stream>>>(feat, npts, coords, W, out, partials, nb);
  k2_reduce<<<138, 256, 0, stream>>>(partials, nb, S);
  k3_finish<<<P_TOT / 4, 256, 0, stream>>>(npts, S, W, gamma, beta, out);
}

// Round 21
// 38.335 us; speedup vs baseline: 1.3250x; 1.3250x over previous
//
#include <hip/hip_runtime.h>

#define P_TOT 30000
#define NPT   100
#define COUT  64

typedef __attribute__((ext_vector_type(8)))  short bf16x8;
typedef __attribute__((ext_vector_type(16))) float f32x16;

static constexpr float VXf   = 0.16f;
static constexpr float VYf   = 0.16f;
static constexpr float XOFFf = 0.08f;            // VX/2 + 0.0
static constexpr float YOFFf = 0.08f - 39.68f;   // VY/2 + y_min
static constexpr float INV_M = 1.0f / 3000000.0f; // 1/(P*N)
static constexpr float NEGI  = -3.0e38f;

__device__ inline float wred(float v) {           // cold paths (K2, epilogue)
#pragma unroll
  for (int d = 1; d < 64; d <<= 1) v += __shfl_xor(v, d);
  return v;
}

// Hot-path wave sum via DPP (canonical gfx9 reduce):
// quad_perm xor1, xor2; row_half_mirror; row_mirror; bcast15->rows1,3;
// bcast31->rows2,3; total lands in lane 63; readlane broadcasts via SGPR.
__device__ inline float wred_dpp(float v) {
  float t;
  t = __int_as_float(__builtin_amdgcn_update_dpp(0, __float_as_int(v), 0xB1, 0xF, 0xF, true));  v += t; // xor1
  t = __int_as_float(__builtin_amdgcn_update_dpp(0, __float_as_int(v), 0x4E, 0xF, 0xF, true));  v += t; // xor2
  t = __int_as_float(__builtin_amdgcn_update_dpp(0, __float_as_int(v), 0x141, 0xF, 0xF, true)); v += t; // row_half_mirror
  t = __int_as_float(__builtin_amdgcn_update_dpp(0, __float_as_int(v), 0x140, 0xF, 0xF, true)); v += t; // row_mirror
  t = __int_as_float(__builtin_amdgcn_update_dpp(0, __float_as_int(v), 0x142, 0xA, 0xF, true)); v += t; // bcast15
  t = __int_as_float(__builtin_amdgcn_update_dpp(0, __float_as_int(v), 0x143, 0xC, 0xF, true)); v += t; // bcast31
  return __int_as_float(__builtin_amdgcn_readlane(__float_as_int(v), 63));
}

// (bf16(hi) << 16) | bf16(lo)
__device__ inline unsigned pack_bf2(float lo, float hi) {
  return (__float_as_uint(hi) & 0xFFFF0000u) | (__float_as_uint(lo) >> 16);
}

union AF { bf16x8 v; unsigned u[4]; };

// 3-op fold: max + add + fma(sumsq). Paired partials break the add chains.
__device__ inline void fold_full(const f32x16& c, float& zm, float& zs, float& zq) {
  float s0 = 0.f, s1 = 0.f, q0 = 0.f, q1 = 0.f;
#pragma unroll
  for (int r = 0; r < 8; ++r) {
    zm = fmaxf(fmaxf(zm, c[2 * r]), c[2 * r + 1]);
    s0 += c[2 * r];
    s1 += c[2 * r + 1];
    q0 = fmaf(c[2 * r], c[2 * r], q0);
    q1 = fmaf(c[2 * r + 1], c[2 * r + 1], q1);
  }
  zs += s0 + s1;
  zq += q0 + q1;
}

// Masked fold with quad-skip: C-reg quad qd covers rows 8qd..8qd+7 (both
// lane halves); skip it entirely (uniform branch) when 8qd >= rem.
// Pad rows are exactly 0 -> skipping them is safe for zs/zq too.
__device__ inline void fold_mask(const f32x16& c, int thresh, int rem,
                                 float& zm, float& zs, float& zq) {
  float s0 = 0.f, s1 = 0.f, q0 = 0.f, q1 = 0.f;
#pragma unroll
  for (int qd = 0; qd < 4; ++qd) {
    if (8 * qd < rem) {     // wave-uniform (rem = np - 32t)
#pragma unroll
      for (int r = 4 * qd; r < 4 * qd + 4; ++r) {
        const int ro = (r & 3) + 8 * (r >> 2);        // compile-time row offset
        zm = fmaxf(zm, (ro < thresh) ? c[r] : NEGI);  // exclude zero pad rows
        if (r & 1) { s1 += c[r]; q1 = fmaf(c[r], c[r], q1); }
        else       { s0 += c[r]; q0 = fmaf(c[r], c[r], q0); }
      }
    }
  }
  zs += s0 + s1;
  zq += q0 + q1;
}

// One MFMA pair (both channel halves) + fold for a tile.
#define TILE_BODY(U0, U1, TFULL, THRESH, REM)                                   \
  {                                                                             \
    unsigned u0_ = (U0), u1_ = (U1);                                            \
    if (lane >= 32) { u0_ = 0u; u1_ = 0u; }  /* k-group 1 = zero pad */         \
    AF af;                                                                      \
    af.u[0] = u0_; af.u[1] = u1_; af.u[2] = 0; af.u[3] = 0;                     \
    {                                                                           \
      f32x16 c0 = __builtin_amdgcn_mfma_f32_32x32x16_bf16(af.v, bf0.v, z16, 0, 0, 0); \
      if (TFULL) fold_full(c0, zm0, zs0, zq0);                                  \
      else       fold_mask(c0, (THRESH), (REM), zm0, zs0, zq0);                 \
    }                                                                           \
    {                                                                           \
      f32x16 c1 = __builtin_amdgcn_mfma_f32_32x32x16_bf16(af.v, bf1.v, z16, 0, 0, 0); \
      if (TFULL) fold_full(c1, zm1, zs1, zq1);                                  \
      else       fold_mask(c1, (THRESH), (REM), zm1, zs1, zq1);                 \
    }                                                                           \
  }

// K1: r19 structure (LDS-free register A-fragments, prefetch, 4 static tiles,
// in-fold 3-op stats) + DPP wave-reduce + quad-skip masked fold.
// Per-pillar epilogue (r7-verified):
//   ymax = zmax + b ; sum += zs + np*b ; sumsq += zq + b*(2*zs + np*b)
__global__ __launch_bounds__(256) void k1_mfma(
    const float4* __restrict__ feat, const int* __restrict__ npts,
    const int* __restrict__ coords, const float* __restrict__ W,
    float* __restrict__ ymax, float* __restrict__ partials, int nb) {
  const int lane = threadIdx.x & 63;
  const int wv   = threadIdx.x >> 6;
  const int wave_id = blockIdx.x * 4 + wv;
  const int nwaves  = nb * 4;
  const int rbase   = (lane >> 5) * 4;

  // per-channel weights, affine-folded: ce = (w0+w4+w7, w1+w5+w8, w2+w6, w3)
  float wr[9];
#pragma unroll
  for (int i = 0; i < 9; i++) wr[i] = W[lane * 9 + i];
  const float ce0 = wr[0] + wr[4] + wr[7];
  const float ce1 = wr[1] + wr[5] + wr[8];
  const float ce2 = wr[2] + wr[6];
  const float ce3 = wr[3];

  // B fragments: lane -> channel n*32+(lane&31), real k=0..3 in slots u0,u1
  AF bf0, bf1;
  {
    const unsigned p01 = pack_bf2(ce0, ce1);
    const unsigned p23 = pack_bf2(ce2, ce3);
    const int s0 = lane & 31, s1 = 32 + (lane & 31);
    unsigned b0a = (unsigned)__shfl((int)p01, s0);
    unsigned b0b = (unsigned)__shfl((int)p23, s0);
    unsigned b1a = (unsigned)__shfl((int)p01, s1);
    unsigned b1b = (unsigned)__shfl((int)p23, s1);
    if (lane >= 32) { b0a = b0b = b1a = b1b = 0; }
    bf0.u[0] = b0a; bf0.u[1] = b0b; bf0.u[2] = 0; bf0.u[3] = 0;
    bf1.u[0] = b1a; bf1.u[1] = b1b; bf1.u[2] = 0; bf1.u[3] = 0;
  }

  const f32x16 z16 = {0.f};
  float sum = 0.f, sumsq = 0.f;

  // prologue: load pillar wave_id
  int p = wave_id;
  float4 a0 = make_float4(0.f, 0.f, 0.f, 0.f), a1 = a0;
  int np = 1, cx = 0, cy = 0;
  if (p < P_TOT) {
    const float4* fp = feat + (size_t)p * NPT;
    a0 = fp[lane];
    if (lane < 36) a1 = fp[lane + 64];
    np = npts[p];
    cx = coords[p * 4 + 3];
    cy = coords[p * 4 + 2];
  }

  while (p < P_TOT) {
    const int pn = p + nwaves;
    float4 b0 = make_float4(0.f, 0.f, 0.f, 0.f), b1 = b0;
    int npn = 1, cxn = 0, cyn = 0;
    if (pn < P_TOT) {
      const float4* fpn = feat + (size_t)pn * NPT;
      b0 = fpn[lane];
      if (lane < 36) b1 = fpn[lane + 64];
      npn = npts[pn];
      cxn = coords[pn * 4 + 3];
      cyn = coords[pn * 4 + 2];
    }

    // pack to bf16, then mask (rows >= np become 0)
    unsigned pk0 = pack_bf2(a0.x, a0.y), pk1 = pack_bf2(a0.z, a0.w);
    unsigned pk2 = pack_bf2(a1.x, a1.y), pk3 = pack_bf2(a1.z, a1.w);
    if (lane >= np)      { pk0 = 0u; pk1 = 0u; }
    if (lane + 64 >= np) { pk2 = 0u; pk3 = 0u; }

    // cross-lane xyz sums from RAW rows via DPP (reference: ALL 100 rows / np)
    const float sax = wred_dpp(a0.x + a1.x);
    const float say = wred_dpp(a0.y + a1.y);
    const float saz = wred_dpp(a0.z + a1.z);
    const float inv = 1.f / (float)np;
    const float cxc = (float)cx * VXf + XOFFf;
    const float cyc = (float)cy * VYf + YOFFf;
    float b = wr[4] * (sax * inv);
    b = fmaf(wr[5], say * inv, b);
    b = fmaf(wr[6], saz * inv, b);
    b = fmaf(wr[7], cxc, b);
    b = fmaf(wr[8], cyc, b);
    b = -b;

    // z-loop: 4 static tiles, A-fragments from registers (no LDS)
    float zm0 = NEGI, zm1 = NEGI;
    float zs0 = 0.f, zs1 = 0.f, zq0 = 0.f, zq1 = 0.f;

    TILE_BODY(pk0, pk1, (np >= 32), np - rbase, np);             // tile 0
    if (np > 32) {                                               // tile 1
      const unsigned s0 = (unsigned)__shfl_xor((int)pk0, 32);
      const unsigned s1 = (unsigned)__shfl_xor((int)pk1, 32);
      TILE_BODY(s0, s1, (np >= 64), np - 32 - rbase, np - 32);
    }
    if (np > 64) {                                               // tile 2
      TILE_BODY(pk2, pk3, (np >= 96), np - 64 - rbase, np - 64);
    }
    if (np > 96) {                                               // tile 3
      const unsigned s2 = (unsigned)__shfl_xor((int)pk2, 32);
      const unsigned s3 = (unsigned)__shfl_xor((int)pk3, 32);
      TILE_BODY(s2, s3, false, np - 96 - rbase, np - 96);
    }

    // combine row-halves, pick this lane's channel half
    zm0 = fmaxf(zm0, __shfl_xor(zm0, 32));
    zm1 = fmaxf(zm1, __shfl_xor(zm1, 32));
    zs0 += __shfl_xor(zs0, 32);
    zs1 += __shfl_xor(zs1, 32);
    zq0 += __shfl_xor(zq0, 32);
    zq1 += __shfl_xor(zq1, 32);
    const float zm = (lane < 32) ? zm0 : zm1;   // channel = lane
    const float zs = (lane < 32) ? zs0 : zs1;
    const float zq = (lane < 32) ? zq0 : zq1;

    const float npf = (float)np;
    ymax[p * COUT + lane] = zm + b;
    sum   += zs + npf * b;
    sumsq += zq + b * fmaf(npf, b, 2.f * zs);

    p = pn;
    a0 = b0; a1 = b1; np = npn; cx = cxn; cy = cyn;
  }

  // block reduction: 64 sum rows, 64 sumsq rows
  __syncthreads();
  __shared__ float rs[4][64], rq[4][64];
  rs[wv][lane] = sum;
  rq[wv][lane] = sumsq;
  __syncthreads();
  const int t = threadIdx.x;
  if (t < 128) {
    const int c = t & 63;
    float v;
    if (t < 64) v = rs[0][c] + rs[1][c] + rs[2][c] + rs[3][c];
    else        v = rq[0][c] + rq[1][c] + rq[2][c] + rq[3][c];
    partials[(size_t)blockIdx.x * 128 + t] = v;   // coalesced, block-major
  }
}

// K2: 128 blocks (one per moment), 256 threads each -> TLP hides latency
__global__ __launch_bounds__(256) void k2_reduce(
    const float* __restrict__ partials, int nb, float* __restrict__ S) {
  const int m = blockIdx.x;
  float s = 0.f;
  for (int b = threadIdx.x; b < nb; b += 256) s += partials[(size_t)b * 128 + m];
  s = wred(s);
  __shared__ float t4[4];
  if ((threadIdx.x & 63) == 0) t4[threadIdx.x >> 6] = s;
  __syncthreads();
  if (threadIdx.x == 0) S[m] = t4[0] + t4[1] + t4[2] + t4[3];
}

// K3: finish in place on d_out. gamma==1 => scale>0, so max commutes with BN.
__global__ __launch_bounds__(256) void k3_finish(
    const int* __restrict__ npts, const float* __restrict__ S,
    const float* __restrict__ gamma, const float* __restrict__ beta,
    float* __restrict__ out) {
  const int c  = threadIdx.x & 63;
  const int wv = threadIdx.x >> 6;
  const int p  = blockIdx.x * 4 + wv;   // 7500*4 == 30000

  const float mean  = S[c] * INV_M;
  const float var   = S[64 + c] * INV_M - mean * mean;
  const float scale = gamma[c] * rsqrtf(var + 0.001f);
  const float shift = beta[c] - mean * scale;

  const int np = npts[p];
  float v = fmaf(scale, out[p * COUT + c], shift);
  if (np < NPT) v = fmaxf(v, shift);   // padded positions contribute relu(shift)
  out[p * COUT + c] = fmaxf(v, 0.f);
}

extern "C" void kernel_launch(void* const* d_in, const int* in_sizes, int n_in,
                              void* d_out, int out_size, void* d_ws, size_t ws_size,
                              hipStream_t stream) {
  const float4* feat  = (const float4*)d_in[0];
  const int*   npts   = (const int*)d_in[1];
  const int*   coords = (const int*)d_in[2];
  const float* W      = (const float*)d_in[3];
  const float* gamma  = (const float*)d_in[4];
  const float* beta   = (const float*)d_in[5];
  float* out = (float*)d_out;

  int nb = 512;
  if (ws_size >= (size_t)(128 + 2048 * 128) * 4) nb = 2048;
  else if (ws_size >= (size_t)(128 + 1024 * 128) * 4) nb = 1024;

  float* S        = (float*)d_ws;   // 128 floats
  float* partials = S + 128;        // nb*128 floats, block-major

  k1_mfma<<<nb, 256, 0, stream>>>(feat, npts, coords, W, out, partials, nb);
  k2_reduce<<<128, 256, 0, stream>>>(partials, nb, S);
  k3_finish<<<P_TOT / 4, 256, 0, stream>>>(npts, S, gamma, beta, out);
}